// Round 4
// baseline (27.975 us; speedup 1.0000x reference)
//
#include <hip/hip_runtime.h>

typedef __attribute__((ext_vector_type(8))) short bf16x8;
typedef __attribute__((ext_vector_type(4))) float f32x4;
typedef unsigned short u16;
typedef unsigned int u32;

__device__ __forceinline__ u16 f2bf(float f) {
    u32 u = __builtin_bit_cast(u32, f);
    return (u16)((u + 0x7FFFu + ((u >> 16) & 1u)) >> 16);
}
__device__ __forceinline__ float sigm(float x) { return 1.f / (1.f + __expf(-x)); }
__device__ __forceinline__ float red16(float x) {
    x += __shfl_xor(x, 1, 64);
    x += __shfl_xor(x, 2, 64);
    x += __shfl_xor(x, 4, 64);
    x += __shfl_xor(x, 8, 64);
    return x;
}
__device__ __forceinline__ uint4 pack8(const float* s) {
    f32x4 v0 = *(const f32x4*)s;
    f32x4 v1 = *(const f32x4*)(s + 4);
    uint4 o;
    o.x = (u32)f2bf(v0.x) | ((u32)f2bf(v0.y) << 16);
    o.y = (u32)f2bf(v0.z) | ((u32)f2bf(v0.w) << 16);
    o.z = (u32)f2bf(v1.x) | ((u32)f2bf(v1.y) << 16);
    o.w = (u32)f2bf(v1.z) | ((u32)f2bf(v1.w) << 16);
    return o;
}

// ---------------- prep: fp32 W -> bf16 W in MFMA-fragment order --------------
// wf layout: [mlp6][c:16][kk:8][lane:64][e:8]  (65536 u16 per mlp)
//   n = c*16 + (lane&15), k = kk*32 + (lane>>4)*8 + e
struct PrepArgs { const float* W[6]; u16* wf; };

__global__ __launch_bounds__(256) void prep_kernel(PrepArgs a) {
    int gid = blockIdx.x * 256 + threadIdx.x;       // 49152 threads
    int l = gid & 63, kk = (gid >> 6) & 7, c = (gid >> 9) & 15, mlp = gid >> 13;
    int n = c * 16 + (l & 15);
    int k0 = kk * 32 + (l >> 4) * 8;
    *(uint4*)(a.wf + (size_t)gid * 8) = pack8(a.W[mlp] + n * 256 + k0);
}

// ---------------- fused: paired GEMM + LN + ReLU + interaction ---------------
// 512 thr = 8 waves. Wave w: gemm g = w>>2 (0=G,1=P), col quarter w4 = w&3
// (cols [w4*64, w4*64+64)). A converted from fp32 in-register. No LDS/barriers
// in the GEMM loop; B-frags stream from L2.
struct PairTask {
    const float *xG, *xP;                   // fp32 inputs [2048][256]
    const u16 *WG, *WP;                     // bf16 B-frag tensors
    const float *bG, *gmG, *beG;
    const float *bP, *gmP, *beP;
    const float *awG, *awP;                 // awG=apw (dots oG), awP=agw (dots oP)
    const float *attbP, *attbG;             // apb, agb
    float *outG, *outP;
    int interact;
};
struct FusedArgs { PairTask p[3]; };

__global__ __launch_bounds__(512, 4) void fused_kernel(FusedArgs args) {
    __shared__ float red_s[2][16][4];
    __shared__ float red_q[2][16][4];
    __shared__ float red_d[2][16][4];
    __shared__ float osh[16][256];          // P-gemm outputs for the combine

    int wg = blockIdx.x;
    int swz = (wg & 7) * 48 + (wg >> 3);    // XCD swizzle, 384 % 8 == 0, bijective
    int pair = swz >> 7;
    int mt = swz & 127;
    PairTask tk = args.p[pair];

    int tid = threadIdx.x;
    int wave = tid >> 6;
    int lane = tid & 63;
    int g = wave >> 2;                      // 0 = G gemm, 1 = P gemm
    int w4 = wave & 3;                      // column quarter
    int cq = lane & 15, rq = lane >> 4;

    // ---- A fragments: own gemm's 16 rows, fp32 load + convert in-register --
    const float* x = g ? tk.xP : tk.xG;
    const float* xrow = x + (size_t)(mt * 16 + cq) * 256 + rq * 8;
    bf16x8 aF[8];
#pragma unroll
    for (int kk = 0; kk < 8; ++kk)
        aF[kk] = __builtin_bit_cast(bf16x8, pack8(xrow + kk * 32));

    const u16* wb = (g ? tk.WP : tk.WG) + lane * 8;

    f32x4 acc[4];
#pragma unroll
    for (int nt = 0; nt < 4; ++nt) acc[nt] = (f32x4){0.f, 0.f, 0.f, 0.f};

    // ---- main loop: 32 independent B loads + 32 MFMAs, no barriers ---------
#pragma unroll
    for (int kk = 0; kk < 8; ++kk) {
#pragma unroll
        for (int nt = 0; nt < 4; ++nt) {
            bf16x8 b = *(const bf16x8*)(wb + (size_t)((w4 * 4 + nt) * 8 + kk) * 512);
            acc[nt] = __builtin_amdgcn_mfma_f32_16x16x32_bf16(aF[kk], b, acc[nt], 0, 0, 0);
        }
    }

    // ---------------------------- epilogue ----------------------------------
    const float* bsel  = g ? tk.bP  : tk.bG;
    const float* gmsel = g ? tk.gmP : tk.gmG;
    const float* besel = g ? tk.beP : tk.beG;
    float bb[4], gm[4], be[4], aw[4];
#pragma unroll
    for (int nt = 0; nt < 4; ++nt) {
        int c = w4 * 64 + nt * 16 + cq;
        bb[nt] = bsel[c];
        gm[nt] = gmsel[c];
        be[nt] = besel[c];
        aw[nt] = tk.interact ? (g ? tk.awP[c] : tk.awG[c]) : 0.f;
    }

    // bias add in place; row stats
#pragma unroll
    for (int r = 0; r < 4; ++r) {
        float s = 0.f, q = 0.f;
#pragma unroll
        for (int nt = 0; nt < 4; ++nt) {
            float t = acc[nt][r] + bb[nt];
            acc[nt][r] = t;
            s += t; q += t * t;
        }
        s = red16(s); q = red16(q);
        if (cq == 0) {
            red_s[g][rq * 4 + r][w4] = s;
            red_q[g][rq * 4 + r][w4] = q;
        }
    }
    __syncthreads();

    // LN + ReLU in place (acc becomes o)
#pragma unroll
    for (int r = 0; r < 4; ++r) {
        int row = rq * 4 + r;
        f32x4 s4 = *(const f32x4*)&red_s[g][row][0];
        f32x4 q4 = *(const f32x4*)&red_q[g][row][0];
        float s = s4.x + s4.y + s4.z + s4.w;
        float q = q4.x + q4.y + q4.z + q4.w;
        float mean = s * (1.f / 256.f);
        float var = q * (1.f / 256.f) - mean * mean;
        float rstd = rsqrtf(var + 1e-5f);
#pragma unroll
        for (int nt = 0; nt < 4; ++nt)
            acc[nt][r] = fmaxf((acc[nt][r] - mean) * rstd * gm[nt] + be[nt], 0.f);
    }

    if (!tk.interact) {
        float* outp = g ? tk.outP : tk.outG;
#pragma unroll
        for (int r = 0; r < 4; ++r) {
            int grow = mt * 16 + rq * 4 + r;
#pragma unroll
            for (int nt = 0; nt < 4; ++nt)
                outp[(size_t)grow * 256 + w4 * 64 + nt * 16 + cq] = acc[nt][r];
        }
    } else {
        // per-row dot partials; P-waves publish their outputs
#pragma unroll
        for (int r = 0; r < 4; ++r) {
            float pd = 0.f;
#pragma unroll
            for (int nt = 0; nt < 4; ++nt) pd += acc[nt][r] * aw[nt];
            pd = red16(pd);
            if (cq == 0) red_d[g][rq * 4 + r][w4] = pd;
        }
        if (g == 1) {
#pragma unroll
            for (int r = 0; r < 4; ++r)
#pragma unroll
                for (int nt = 0; nt < 4; ++nt)
                    osh[rq * 4 + r][w4 * 64 + nt * 16 + cq] = acc[nt][r];
        }
        __syncthreads();
        if (g == 0) {
            float battP = *tk.attbP, battG = *tk.attbG;
#pragma unroll
            for (int r = 0; r < 4; ++r) {
                int row = rq * 4 + r;
                f32x4 d4 = *(const f32x4*)&red_d[0][row][0];
                f32x4 e4 = *(const f32x4*)&red_d[1][row][0];
                float dG = d4.x + d4.y + d4.z + d4.w;   // dot(g_align, apw)
                float dP = e4.x + e4.y + e4.z + e4.w;   // dot(p_align, agw)
                int grow = mt * 16 + row;
#pragma unroll
                for (int nt = 0; nt < 4; ++nt) {
                    int c = w4 * 64 + nt * 16 + cq;
                    float og = acc[nt][r];
                    float op = osh[row][c];
                    tk.outG[(size_t)grow * 256 + c] =
                        op * sigm(op * dG + battP) + og * sigm(og * dP + battG);
                }
            }
        }
    }
}

// -----------------------------------------------------------------------------
extern "C" void kernel_launch(void* const* d_in, const int* in_sizes, int n_in,
                              void* d_out, int out_size, void* d_ws, size_t ws_size,
                              hipStream_t stream) {
    const float* gfeat = (const float*)d_in[0];
    const float* pfeat = (const float*)d_in[1];
    float* out = (float*)d_out;
    const size_t S = (size_t)2048 * 256;

    float* out_common = out + 0 * S;
    float* out_syn    = out + 1 * S;
    float* out_gspec  = out + 2 * S;
    float* out_pspec  = out + 3 * S;

    u16* wf = (u16*)d_ws;                   // 6 * 65536 u16

    PrepArgs pa;
    pa.W[0] = (const float*)d_in[2];    // gs_W
    pa.W[1] = (const float*)d_in[6];    // ps_W
    pa.W[2] = (const float*)d_in[10];   // c_g_W
    pa.W[3] = (const float*)d_in[14];   // c_p_W
    pa.W[4] = (const float*)d_in[22];   // s_g_W
    pa.W[5] = (const float*)d_in[26];   // s_p_W
    pa.wf = wf;
    hipLaunchKernelGGL(prep_kernel, dim3(192), dim3(256), 0, stream, pa);

    FusedArgs fa;
    // pair 0: spec — G: mlp(gfeat, gs_*) -> g_spec ; P: mlp(pfeat, ps_*) -> p_spec
    fa.p[0] = { gfeat, pfeat, wf + 0 * 65536, wf + 1 * 65536,
                (const float*)d_in[3], (const float*)d_in[4], (const float*)d_in[5],
                (const float*)d_in[7], (const float*)d_in[8], (const float*)d_in[9],
                nullptr, nullptr, nullptr, nullptr,
                out_gspec, out_pspec, 0 };
    // pair 1: common — G: mlp(pfeat, c_g_*), P: mlp(gfeat, c_p_*)
    fa.p[1] = { pfeat, gfeat, wf + 2 * 65536, wf + 3 * 65536,
                (const float*)d_in[11], (const float*)d_in[12], (const float*)d_in[13],
                (const float*)d_in[15], (const float*)d_in[16], (const float*)d_in[17],
                (const float*)d_in[20] /*c_apw*/, (const float*)d_in[18] /*c_agw*/,
                (const float*)d_in[21] /*c_apb*/, (const float*)d_in[19] /*c_agb*/,
                out_common, nullptr, 1 };
    // pair 2: synergy — G: mlp(pfeat, s_g_*), P: mlp(gfeat, s_p_*)
    fa.p[2] = { pfeat, gfeat, wf + 4 * 65536, wf + 5 * 65536,
                (const float*)d_in[23], (const float*)d_in[24], (const float*)d_in[25],
                (const float*)d_in[27], (const float*)d_in[28], (const float*)d_in[29],
                (const float*)d_in[32] /*s_apw*/, (const float*)d_in[30] /*s_agw*/,
                (const float*)d_in[33] /*s_apb*/, (const float*)d_in[31] /*s_agb*/,
                out_syn, nullptr, 1 };

    hipLaunchKernelGGL(fused_kernel, dim3(384), dim3(512), 0, stream, fa);
}